// Round 11
// baseline (291.312 us; speedup 1.0000x reference)
//
#include <hip/hip_runtime.h>
#include <hip/hip_bf16.h>
#include <hip/hip_fp16.h>

typedef __attribute__((ext_vector_type(2))) _Float16 f16x2;
typedef __attribute__((ext_vector_type(8))) _Float16 f16x8;
typedef __attribute__((ext_vector_type(4))) float    f32x4;

#define GRID_ELEMS (8*64*64*64)   // 2,097,152 voxels at level 0
#define ZERO_U4    540801         // (GRID_ELEMS*4 + 65536*4 + 512*4 + 16)/16

// ------------------------------------------------------------- fast zeroer
// zeroes gpk + spart + cntB + done-counter (contiguous).
__global__ __launch_bounds__(256) void zero_k(uint4* __restrict__ p)
{
  const unsigned i = blockIdx.x * 256 + threadIdx.x;
  if (i < ZERO_U4) p[i] = (uint4){0u, 0u, 0u, 0u};
}

// --------------------------------------------- scatter + weight-repack combo
// blocks [0,44): pre-fragment W1/W2/W3 into per-lane MFMA A-frag order.
// blocks [44,..): scatter points — ONE packed-f16 atomic adds (feat, 1.0)
// into gpk[voxel] = {lo: f16 value-sum, hi: f16 point-count}.
__global__ __launch_bounds__(256) void scatter_setup_k(
    const int* __restrict__ coords, const float* __restrict__ feats,
    const float* __restrict__ W1, const float* __restrict__ W2, const float* __restrict__ W3,
    __half2* __restrict__ gpk,
    uint4* __restrict__ W1f, uint4* __restrict__ W2f,
    uint4* __restrict__ W3fA, uint4* __restrict__ W3fB, int N)
{
  const int bi = blockIdx.x;
  if (bi < 44) {
    const int i = bi * 256 + threadIdx.x;
    if (i < 2048) {                       // W2f[(wid*8+ks)*64+lane]
      const int wid = i >> 9, ks = (i >> 6) & 7, lane = i & 63;
      const int l15 = lane & 15, l4 = lane >> 4, o = wid * 16 + l15;
      f16x8 v;
      #pragma unroll
      for (int j = 0; j < 8; ++j)          // k = ks*32 + l4*8 + j -> p=ks, c=l4*8+j
        v[j] = (_Float16)W2[ks * 2048 + (l4 * 8 + j) * 64 + o];
      W2f[i] = __builtin_bit_cast(uint4, v);
    } else if (i < 10240) {               // W3fA/B[(wid*16+ks)*64+lane]
      const int e = i - 2048, ab = e >> 12, r = e & 4095;
      const int wid = r >> 10, ks = (r >> 6) & 15, lane = r & 63;
      const int l15 = lane & 15, l4 = lane >> 4, o = wid * 32 + l15 + ab * 16;
      f16x8 v;
      #pragma unroll
      for (int j = 0; j < 8; ++j)          // k = ks*32+l4*8+j -> p=ks>>1, c=(ks&1)*32+l4*8+j
        v[j] = (_Float16)W3[(ks >> 1) * 8192 + ((ks & 1) * 32 + l4 * 8 + j) * 128 + o];
      (ab ? W3fB : W3fA)[r] = __builtin_bit_cast(uint4, v);
    } else if (i < 10368) {               // W1f[mt*64+lane]: A[m=ch][k=tap], k pad 27->32
      const int t = i - 10240;
      const int mt = t >> 6, l = t & 63;
      f16x8 v;
      #pragma unroll
      for (int j = 0; j < 8; ++j) {
        const int k = (l >> 4) * 8 + j;
        v[j] = (k < 27) ? (_Float16)W1[k * 32 + mt * 16 + (l & 15)] : (_Float16)0;
      }
      W1f[t] = __builtin_bit_cast(uint4, v);
    }
    return;
  }
  const int i = (bi - 44) * 256 + threadIdx.x;
  if (i >= N) return;
  const int4 c = reinterpret_cast<const int4*>(coords)[i];
  const int idx = ((c.x * 64 + c.y) * 64 + c.z) * 64 + c.w;
  const __half2 v = __halves2half2(__float2half_rn(feats[i]), __float2half_rn(1.0f));
  unsafeAtomicAdd(&gpk[idx], v);         // global_atomic_pk_add_f16
}

// --------------------------------------------------------------- megakernel
// Block = octant pair: 4x4x8 l2-voxels (8x8x16 l1, 2x2x4 l3). 2048 blocks.
// LDS 31.8 KB -> 5 blocks/CU. l1 mask lives in a 16-bit register (mbits);
// m2s derived straight from gpk. Epilogues: f32 relu -> cvt_pkrtz -> AND-mask.
// Last finished block reduces the buckets and runs the FC (no extra launch).
__global__ __launch_bounds__(256, 4) void mega_k(
    const unsigned* __restrict__ gpk,
    const uint4* __restrict__ W1f, const uint4* __restrict__ W2f,
    const uint4* __restrict__ W3fA, const uint4* __restrict__ W3fB,
    float* __restrict__ spart, float* __restrict__ cntB,
    unsigned* __restrict__ donecnt,
    const float* __restrict__ fc_w, const float* __restrict__ fc_b,
    float* __restrict__ out)
{
  // LDS carve (31,840 B): [h2s0 11264][h1f 16384 (h2s1 overlays)]
  // [tile 3600][m2s 512][m3s 64][lastf 4]
  __shared__ __align__(16) char smem[31840];
  _Float16* const h1f  = (_Float16*)(smem + 11264);
  _Float16* const tile = (_Float16*)(smem + 27648);        // [10][10][18]
  float*    const m2s  = (float*)(smem + 31248);           // [4][4][8]
  float*    const m3s  = (float*)(smem + 31760);           // [2][2][4]
  int*      const lastf = (int*)(smem + 31824);

  const int tid = threadIdx.x;
  const int bid = blockIdx.x;
  const int b   = bid >> 8;
  const int X2  = (bid >> 5) & 7, Y2 = (bid >> 2) & 7, Zp = bid & 3;
  const int gb  = b << 18;
  const int lane = tid & 63, wid = tid >> 6;
  const int l15 = lane & 15, l4 = lane >> 4;

  // ---- phase 0: stage grid tile (f16 value half of gpk)
  {
    const int gx0 = X2 * 8 - 1, gy0 = Y2 * 8 - 1, gz0 = Zp * 16 - 1;
    for (int e = tid; e < 1800; e += 256) {
      const int x = e / 180, r = e - x * 180, y = r / 18, z = r - y * 18;
      const int gx = gx0 + x, gy = gy0 + y, gz = gz0 + z;
      const bool ok = ((unsigned)gx < 64u) & ((unsigned)gy < 64u) & ((unsigned)gz < 64u);
      const unsigned g = ok ? gpk[gb + (gx << 12) + (gy << 6) + gz] : 0u;
      tile[e] = __builtin_bit_cast(_Float16, (unsigned short)(g & 0xffffu));
    }
  }

  // ---- l1 mask bits for this thread's 16 conv1 voxels (cnt half of gpk)
  unsigned mbits = 0;
  #pragma unroll
  for (int it = 0; it < 16; ++it) {
    const int o = it >> 3, cc = (it >> 2) & 1, gi = it & 3;
    const int idx = (wid * 4 + gi) * 16 + l15;
    const int x1 = 2 * (idx >> 6) + cc, y1 = (idx >> 3) & 7, zo = idx & 7;
    const int gx = X2 * 8 + x1, gy = Y2 * 8 + y1, gz = Zp * 16 + o * 8 + zo;
    if (gpk[gb + (gx << 12) + (gy << 6) + gz] >> 16) mbits |= 1u << it;
  }

  // ---- m2s straight from gpk (l2 mask = any of 8 children occupied)
  if (tid < 128) {
    const int x2 = tid >> 5, y2 = (tid >> 3) & 3, z2 = tid & 7;
    const int gx = X2 * 8 + 2 * x2, gy = Y2 * 8 + 2 * y2, gz = Zp * 16 + 2 * z2;
    unsigned m = 0;
    #pragma unroll
    for (int p = 0; p < 8; ++p)
      m |= gpk[gb + ((gx + (p >> 2)) << 12) + ((gy + ((p >> 1) & 1)) << 6) + (gz + (p & 1))] >> 16;
    m2s[tid] = m ? 1.f : 0.f;
  }

  // W-frag preloads (L2; latency hidden under phase 0)
  const uint4 w1a = W1f[lane];
  const uint4 w1b = W1f[64 + lane];
  uint4 w2r[8];
  #pragma unroll
  for (int ks = 0; ks < 8; ++ks) w2r[ks] = W2f[(wid * 8 + ks) * 64 + lane];

  // tap byte-offsets, computed arithmetically (pad k>=27 -> offset 0)
  int t_off[8];
  #pragma unroll
  for (int j = 0; j < 8; ++j) {
    const int k = l4 * 8 + j;
    int off = 0;
    if (k < 27) {
      const int tx = k / 9, rr = k - 9 * tx, ty = rr / 3, tz = rr - 3 * ty;
      off = (tx * 180 + ty * 18 + tz) * 2;
    }
    t_off[j] = off;
  }

  __syncthreads();

  if (tid < 16) {   // m3 = max over 8 l2 children; [x3 2][y3 2][z3 4]
    const int base = ((tid >> 3) << 6) + (((tid >> 2) & 1) << 4) + ((tid & 3) << 1);
    float m = m2s[base];
    m = fmaxf(m, m2s[base + 1]);  m = fmaxf(m, m2s[base + 8]);
    m = fmaxf(m, m2s[base + 9]);  m = fmaxf(m, m2s[base + 32]);
    m = fmaxf(m, m2s[base + 33]); m = fmaxf(m, m2s[base + 40]);
    m = fmaxf(m, m2s[base + 41]);
    m3s[tid] = m;
  }

  const char* tilec = (const char*)tile;
  uint4 wa[4], wb2[4];                    // W3 pipeline regs (filled at o==1)

  #pragma unroll
  for (int o = 0; o < 2; ++o) {
    f32x4 acc[4];
    #pragma unroll
    for (int nt = 0; nt < 4; ++nt) acc[nt] = (f32x4){0.f, 0.f, 0.f, 0.f};

    #pragma unroll
    for (int cc = 0; cc < 2; ++cc) {
      // conv1 MFMA chunk: l1 voxels of octant o with x1 parity cc
      #pragma unroll
      for (int gi = 0; gi < 4; ++gi) {
        const int idx = (wid * 4 + gi) * 16 + l15;
        const int x1 = 2 * (idx >> 6) + cc, y1 = (idx >> 3) & 7, zo = idx & 7;
        const int z1 = o * 8 + zo;
        const int base2 = (x1 * 180 + y1 * 18 + z1) * 2;
        f16x8 bf;
        #pragma unroll
        for (int j = 0; j < 8; ++j)
          bf[j] = *reinterpret_cast<const _Float16*>(tilec + base2 + t_off[j]);
        f32x4 aA = (f32x4){0.f, 0.f, 0.f, 0.f};
        f32x4 aB = (f32x4){0.f, 0.f, 0.f, 0.f};
        aA = __builtin_amdgcn_mfma_f32_16x16x32_f16(__builtin_bit_cast(f16x8, w1a), bf, aA, 0, 0, 0);
        aB = __builtin_amdgcn_mfma_f32_16x16x32_f16(__builtin_bit_cast(f16x8, w1b), bf, aB, 0, 0, 0);

        // epilogue: f32 relu -> cvt_pkrtz -> AND with 0/1 mask bits
        const unsigned umask = (mbits >> (o * 8 + cc * 4 + gi)) & 1u ? 0xffffffffu : 0u;
        const int p_l = ((y1 & 1) << 1) | (zo & 1);
        const int v2  = ((x1 >> 1) << 4) | ((y1 >> 1) << 2) | (zo >> 1);
        const int fbase = (((v2 >> 4) * 4 + p_l) * 64 + (v2 & 15)) * 8 + (l4 & 1) * 4;
        const int qsel = l4 >> 1;
        uint2 wA, wB;
        {
          const auto c0 = __builtin_amdgcn_cvt_pkrtz(fmaxf(aA[0], 0.f), fmaxf(aA[1], 0.f));
          const auto c1 = __builtin_amdgcn_cvt_pkrtz(fmaxf(aA[2], 0.f), fmaxf(aA[3], 0.f));
          wA.x = __builtin_bit_cast(unsigned, c0) & umask;
          wA.y = __builtin_bit_cast(unsigned, c1) & umask;
        }
        {
          const auto c0 = __builtin_amdgcn_cvt_pkrtz(fmaxf(aB[0], 0.f), fmaxf(aB[1], 0.f));
          const auto c1 = __builtin_amdgcn_cvt_pkrtz(fmaxf(aB[2], 0.f), fmaxf(aB[3], 0.f));
          wB.x = __builtin_bit_cast(unsigned, c0) & umask;
          wB.y = __builtin_bit_cast(unsigned, c1) & umask;
        }
        *reinterpret_cast<uint2*>(&h1f[fbase + qsel * 128])       = wA;   // ch 0-15
        *reinterpret_cast<uint2*>(&h1f[fbase + (2 + qsel) * 128]) = wB;   // ch 16-31
      }
      __syncthreads();                    // h1f chunk ready

      // conv2 partial: K-steps cc*4 .. cc*4+3
      #pragma unroll
      for (int ks = 0; ks < 4; ++ks) {
        const f16x8 af = __builtin_bit_cast(f16x8, w2r[cc * 4 + ks]);
        #pragma unroll
        for (int nt = 0; nt < 4; ++nt) {
          const f16x8 bb = *reinterpret_cast<const f16x8*>(&h1f[((nt * 4 + ks) * 64 + lane) * 8]);
          acc[nt] = __builtin_amdgcn_mfma_f32_16x16x32_f16(af, bb, acc[nt], 0, 0, 0);
        }
      }

      if (o == 1 && cc == 1) {            // prefetch W3 chunk 0 under barrier+epilogue
        #pragma unroll
        for (int j = 0; j < 4; ++j) {
          wa[j]  = W3fA[(wid * 16 + j) * 64 + lane];
          wb2[j] = W3fB[(wid * 16 + j) * 64 + lane];
        }
      }
      __syncthreads();                    // conv2 reads done (h1f reusable)
    }

    // conv2 epilogue: f32 relu -> cvt_pkrtz -> AND m2 mask -> h2s[o]
    _Float16* const h2o = (_Float16*)(smem + o * 11264);
    const int o0 = wid * 16 + l4 * 4;
    #pragma unroll
    for (int nt = 0; nt < 4; ++nt) {
      const int v2l = nt * 16 + l15;
      const float m2v = m2s[((v2l >> 4) << 5) + (((v2l >> 2) & 3) << 3) + o * 4 + (v2l & 3)];
      const unsigned um = (m2v != 0.f) ? 0xffffffffu : 0u;
      const auto p0 = __builtin_amdgcn_cvt_pkrtz(fmaxf(acc[nt][0], 0.f), fmaxf(acc[nt][1], 0.f));
      const auto p1 = __builtin_amdgcn_cvt_pkrtz(fmaxf(acc[nt][2], 0.f), fmaxf(acc[nt][3], 0.f));
      uint2 u;
      u.x = __builtin_bit_cast(unsigned, p0) & um;
      u.y = __builtin_bit_cast(unsigned, p1) & um;
      *reinterpret_cast<uint2*>(&h2o[v2l * 88 + o0]) = u;
    }
  }
  __syncthreads();                        // h2s0 + h2s1 ready

  // ---- conv3 MFMA: N=16 l3-voxels (both octants), K=512, pipelined W3 stream
  f32x4 c3a = (f32x4){0.f,0.f,0.f,0.f};
  f32x4 c3b = (f32x4){0.f,0.f,0.f,0.f};
  const int v3 = l15;                     // [x3 2][y3 2][z3 4]
  const int x3 = v3 >> 3, y3 = (v3 >> 2) & 1, z3 = v3 & 3;
  const int obyte = (z3 >> 1) * 11264;

  #pragma unroll
  for (int kc = 0; kc < 4; ++kc) {
    uint4 na[4], nb[4];
    if (kc < 3) {
      #pragma unroll
      for (int j = 0; j < 4; ++j) {
        na[j] = W3fA[(wid * 16 + (kc + 1) * 4 + j) * 64 + lane];
        nb[j] = W3fB[(wid * 16 + (kc + 1) * 4 + j) * 64 + lane];
      }
    }
    #pragma unroll
    for (int j = 0; j < 4; ++j) {
      const int ks = kc * 4 + j;
      const int p = ks >> 1;
      const int x2 = 2 * x3 + (p >> 2), y2 = 2 * y3 + ((p >> 1) & 1);
      const int z2l = 2 * (z3 & 1) + (p & 1);
      const int v2l = (x2 << 4) | (y2 << 2) | z2l;
      const int c0 = (ks & 1) * 32 + l4 * 8;
      const f16x8 bf = *reinterpret_cast<const f16x8*>(smem + obyte + (v2l * 88 + c0) * 2);
      c3a = __builtin_amdgcn_mfma_f32_16x16x32_f16(__builtin_bit_cast(f16x8, wa[j]),  bf, c3a, 0, 0, 0);
      c3b = __builtin_amdgcn_mfma_f32_16x16x32_f16(__builtin_bit_cast(f16x8, wb2[j]), bf, c3b, 0, 0, 0);
    }
    if (kc < 3) {
      #pragma unroll
      for (int j = 0; j < 4; ++j) { wa[j] = na[j]; wb2[j] = nb[j]; }
    }
  }

  // relu * m3, reduce over the 16 voxel-lanes, bucket atomics
  const float m3v = m3s[v3];
  float part[2][4];
  #pragma unroll
  for (int j = 0; j < 4; ++j) {
    part[0][j] = fmaxf(c3a[j], 0.f) * m3v;
    part[1][j] = fmaxf(c3b[j], 0.f) * m3v;
  }
  #pragma unroll
  for (int d = 1; d < 16; d <<= 1) {
    #pragma unroll
    for (int mt = 0; mt < 2; ++mt)
      #pragma unroll
      for (int j = 0; j < 4; ++j)
        part[mt][j] += __shfl_xor(part[mt][j], d, 64);
  }
  if (l15 == 0) {
    const int sb = (b * 64 + (bid & 63)) * 128 + wid * 32;
    #pragma unroll
    for (int mt = 0; mt < 2; ++mt)
      #pragma unroll
      for (int j = 0; j < 4; ++j)
        atomicAdd(&spart[sb + mt * 16 + l4 * 4 + j], part[mt][j]);
  }
  if (tid == 0) {
    float t = 0.f;
    #pragma unroll
    for (int i = 0; i < 16; ++i) t += m3s[i];
    atomicAdd(&cntB[b * 64 + (bid & 63)], t);
  }

  // ---- last finished block: bucket reduce + FC (replaces reduce_fc launch)
  __threadfence();
  if (tid == 0)
    *lastf = (__hip_atomic_fetch_add(donecnt, 1u, __ATOMIC_ACQ_REL,
                                     __HIP_MEMORY_SCOPE_AGENT) == 2047u);
  __syncthreads();
  if (!*lastf) return;

  float* const s_l  = (float*)smem;            // 4 KB (smem fully dead now)
  float* const invb = (float*)(smem + 4096);   // 8 floats
  for (int p2 = tid; p2 < 1024; p2 += 256) {
    const int bb = p2 >> 7, ch = p2 & 127;
    float a = 0.f;
    #pragma unroll 4
    for (int g = 0; g < 64; ++g)
      a += __hip_atomic_load(&spart[(bb * 64 + g) * 128 + ch],
                             __ATOMIC_RELAXED, __HIP_MEMORY_SCOPE_AGENT);
    s_l[p2] = a;
  }
  if (tid < 8) {
    float a = 0.f;
    for (int g = 0; g < 64; ++g)
      a += __hip_atomic_load(&cntB[tid * 64 + g],
                             __ATOMIC_RELAXED, __HIP_MEMORY_SCOPE_AGENT);
    invb[tid] = 1.f / fmaxf(a, 1.f);
  }
  __syncthreads();

  float o8[8];
  #pragma unroll
  for (int bb = 0; bb < 8; ++bb) o8[bb] = fc_b[tid];
  for (int c = 0; c < 128; ++c) {
    const float w = fc_w[c * 256 + tid];
    #pragma unroll
    for (int bb = 0; bb < 8; ++bb)
      o8[bb] = fmaf(s_l[bb * 128 + c] * invb[bb], w, o8[bb]);
  }
  #pragma unroll
  for (int bb = 0; bb < 8; ++bb) out[bb * 256 + tid] = o8[bb];
}

// ---------------------------------------------------------------- launch
extern "C" void kernel_launch(void* const* d_in, const int* in_sizes, int n_in,
                              void* d_out, int out_size, void* d_ws, size_t ws_size,
                              hipStream_t stream)
{
  const int*   coords = (const int*)  d_in[0];
  const float* feats  = (const float*)d_in[1];
  const float* W1     = (const float*)d_in[2];
  const float* W2     = (const float*)d_in[3];
  const float* W3     = (const float*)d_in[4];
  const float* fc_w   = (const float*)d_in[5];
  const float* fc_b   = (const float*)d_in[6];
  float* out = (float*)d_out;
  const int N = in_sizes[0] / 4;

  unsigned* gpk   = (unsigned*)d_ws;                 // 8.39 MB (f16 val, f16 cnt)
  float*    spart = (float*)(gpk + GRID_ELEMS);      // 256 KB (8 x 64 x 128)
  float*    cntB  = spart + 8 * 64 * 128;            // 2 KB
  unsigned* done  = (unsigned*)(cntB + 512);         // 16 B slot
  uint4*    W1f   = (uint4*)((char*)d_ws + 8652816); // 2 KB (128 uint4)
  uint4*    W2f   = W1f + 128;                       // 32 KB
  uint4*    W3fA  = W2f + 2048;                      // 64 KB
  uint4*    W3fB  = W3fA + 4096;                     // 64 KB
  // total ws use: ~8.8 MB

  zero_k<<<(ZERO_U4 + 255) / 256, 256, 0, stream>>>((uint4*)gpk);
  scatter_setup_k<<<44 + (N + 255) / 256, 256, 0, stream>>>(
      coords, feats, W1, W2, W3, (__half2*)gpk, W1f, W2f, W3fA, W3fB, N);
  mega_k<<<2048, 256, 0, stream>>>(gpk, W1f, W2f, W3fA, W3fB, spart, cntB,
                                   done, fc_w, fc_b, out);
}

// Round 12
// 69.066 us; speedup vs baseline: 4.2179x; 4.2179x over previous
//
#include <hip/hip_runtime.h>
#include <hip/hip_bf16.h>
#include <hip/hip_fp16.h>

typedef __attribute__((ext_vector_type(2))) _Float16 f16x2;
typedef __attribute__((ext_vector_type(8))) _Float16 f16x8;
typedef __attribute__((ext_vector_type(4))) float    f32x4;

#define GRID_ELEMS (8*64*64*64)   // 2,097,152 voxels at level 0
#define ZERO_U4    540800         // (GRID_ELEMS*4 + 65536*4 + 512*4) / 16

// ------------------------------------------------------------- fast zeroer
__global__ __launch_bounds__(256) void zero_k(uint4* __restrict__ p)
{
  const unsigned i = blockIdx.x * 256 + threadIdx.x;
  if (i < ZERO_U4) p[i] = (uint4){0u, 0u, 0u, 0u};
}

// --------------------------------------------- scatter + weight-repack combo
// blocks [0,44): pre-fragment W1/W2/W3 into per-lane MFMA A-frag order.
// blocks [44,..): scatter points — ONE packed-f16 atomic adds (feat, 1.0)
// into gpk[voxel] = {lo: f16 value-sum, hi: f16 point-count}.
__global__ __launch_bounds__(256) void scatter_setup_k(
    const int* __restrict__ coords, const float* __restrict__ feats,
    const float* __restrict__ W1, const float* __restrict__ W2, const float* __restrict__ W3,
    __half2* __restrict__ gpk,
    uint4* __restrict__ W1f, uint4* __restrict__ W2f,
    uint4* __restrict__ W3fA, uint4* __restrict__ W3fB, int N)
{
  const int bi = blockIdx.x;
  if (bi < 44) {
    const int i = bi * 256 + threadIdx.x;
    if (i < 2048) {                       // W2f[(wid*8+ks)*64+lane]
      const int wid = i >> 9, ks = (i >> 6) & 7, lane = i & 63;
      const int l15 = lane & 15, l4 = lane >> 4, o = wid * 16 + l15;
      f16x8 v;
      #pragma unroll
      for (int j = 0; j < 8; ++j)          // k = ks*32 + l4*8 + j -> p=ks, c=l4*8+j
        v[j] = (_Float16)W2[ks * 2048 + (l4 * 8 + j) * 64 + o];
      W2f[i] = __builtin_bit_cast(uint4, v);
    } else if (i < 10240) {               // W3fA/B[(wid*16+ks)*64+lane]
      const int e = i - 2048, ab = e >> 12, r = e & 4095;
      const int wid = r >> 10, ks = (r >> 6) & 15, lane = r & 63;
      const int l15 = lane & 15, l4 = lane >> 4, o = wid * 32 + l15 + ab * 16;
      f16x8 v;
      #pragma unroll
      for (int j = 0; j < 8; ++j)          // k = ks*32+l4*8+j -> p=ks>>1, c=(ks&1)*32+l4*8+j
        v[j] = (_Float16)W3[(ks >> 1) * 8192 + ((ks & 1) * 32 + l4 * 8 + j) * 128 + o];
      (ab ? W3fB : W3fA)[r] = __builtin_bit_cast(uint4, v);
    } else if (i < 10368) {               // W1f[mt*64+lane]: A[m=ch][k=tap], k pad 27->32
      const int t = i - 10240;
      const int mt = t >> 6, l = t & 63;
      f16x8 v;
      #pragma unroll
      for (int j = 0; j < 8; ++j) {
        const int k = (l >> 4) * 8 + j;
        v[j] = (k < 27) ? (_Float16)W1[k * 32 + mt * 16 + (l & 15)] : (_Float16)0;
      }
      W1f[t] = __builtin_bit_cast(uint4, v);
    }
    return;
  }
  const int i = (bi - 44) * 256 + threadIdx.x;
  if (i >= N) return;
  const int4 c = reinterpret_cast<const int4*>(coords)[i];
  const int idx = ((c.x * 64 + c.y) * 64 + c.z) * 64 + c.w;
  const __half2 v = __halves2half2(__float2half_rn(feats[i]), __float2half_rn(1.0f));
  unsafeAtomicAdd(&gpk[idx], v);         // global_atomic_pk_add_f16
}

// --------------------------------------------------------------- megakernel
// Block = octant pair: 4x4x8 l2-voxels (8x8x16 l1, 2x2x4 l3). 2048 blocks.
// Round-10 structure (known-good 39us) + cvt_pkrtz/AND epilogues and
// register tap offsets. NO device-scope fences / fused FC (round-11's
// threadfence+acq-rel tail caused a serialized L2-flush storm, 295us).
__global__ __launch_bounds__(256, 4) void mega_k(
    const unsigned* __restrict__ gpk,
    const uint4* __restrict__ W1f, const uint4* __restrict__ W2f,
    const uint4* __restrict__ W3fA, const uint4* __restrict__ W3fB,
    float* __restrict__ spart, float* __restrict__ cntB)
{
  // LDS carve (35,920 B): [h2s0 11264][h1f 16384 (h2s1 overlays)]
  // [tile 3600][m1v 4096][m2s 512][m3s 64]
  __shared__ __align__(16) char smem[35920];
  _Float16* const h1f  = (_Float16*)(smem + 11264);
  _Float16* const tile = (_Float16*)(smem + 27648);        // [10][10][18]
  float*    const m1v  = (float*)(smem + 31248);           // [8][8][16]
  float*    const m2s  = (float*)(smem + 35344);           // [4][4][8]
  float*    const m3s  = (float*)(smem + 35856);           // [2][2][4]

  const int tid = threadIdx.x;
  const int bid = blockIdx.x;
  const int b   = bid >> 8;
  const int X2  = (bid >> 5) & 7, Y2 = (bid >> 2) & 7, Zp = bid & 3;
  const int gb  = b << 18;
  const int lane = tid & 63, wid = tid >> 6;
  const int l15 = lane & 15, l4 = lane >> 4;

  // ---- phase 0: stage grid tile (f16 val half) + l1 mask (cnt half)
  {
    const int gx0 = X2 * 8 - 1, gy0 = Y2 * 8 - 1, gz0 = Zp * 16 - 1;
    for (int e = tid; e < 1800; e += 256) {
      const int x = e / 180, r = e - x * 180, y = r / 18, z = r - y * 18;
      const int gx = gx0 + x, gy = gy0 + y, gz = gz0 + z;
      const bool ok = ((unsigned)gx < 64u) & ((unsigned)gy < 64u) & ((unsigned)gz < 64u);
      const unsigned g = ok ? gpk[gb + (gx << 12) + (gy << 6) + gz] : 0u;
      tile[e] = __builtin_bit_cast(_Float16, (unsigned short)(g & 0xffffu));
      const int ix = x - 1, iy = y - 1, iz = z - 1;
      if (((unsigned)ix < 8u) & ((unsigned)iy < 8u) & ((unsigned)iz < 16u))
        m1v[(ix << 7) + (iy << 4) + iz] = (g >> 16) ? 1.f : 0.f;
    }
  }

  // W-frag preloads (L2; latency hidden under phase 0)
  const uint4 w1a = W1f[lane];
  const uint4 w1b = W1f[64 + lane];
  uint4 w2r[8];
  #pragma unroll
  for (int ks = 0; ks < 8; ++ks) w2r[ks] = W2f[(wid * 8 + ks) * 64 + lane];

  // tap byte-offsets, computed arithmetically (pad k>=27 -> offset 0)
  int t_off[8];
  #pragma unroll
  for (int j = 0; j < 8; ++j) {
    const int k = l4 * 8 + j;
    int off = 0;
    if (k < 27) {
      const int tx = k / 9, rr = k - 9 * tx, ty = rr / 3, tz = rr - 3 * ty;
      off = (tx * 180 + ty * 18 + tz) * 2;
    }
    t_off[j] = off;
  }

  __syncthreads();

  if (tid < 128) {   // m2 = max over 8 l1 children; [x2][y2][z2] 4x4x8
    const int base = ((tid >> 5) << 8) + (((tid >> 3) & 3) << 5) + ((tid & 7) << 1);
    float m = m1v[base];
    m = fmaxf(m, m1v[base + 1]);   m = fmaxf(m, m1v[base + 16]);
    m = fmaxf(m, m1v[base + 17]);  m = fmaxf(m, m1v[base + 128]);
    m = fmaxf(m, m1v[base + 129]); m = fmaxf(m, m1v[base + 144]);
    m = fmaxf(m, m1v[base + 145]);
    m2s[tid] = m;
  }

  const char* tilec = (const char*)tile;
  uint4 wa[4], wb2[4];                    // W3 pipeline regs (filled at o==1)

  #pragma unroll
  for (int o = 0; o < 2; ++o) {
    f32x4 acc[4];
    #pragma unroll
    for (int nt = 0; nt < 4; ++nt) acc[nt] = (f32x4){0.f, 0.f, 0.f, 0.f};

    #pragma unroll
    for (int cc = 0; cc < 2; ++cc) {
      // conv1 MFMA chunk: l1 voxels of octant o with x1 parity cc
      #pragma unroll
      for (int gi = 0; gi < 4; ++gi) {
        const int idx = (wid * 4 + gi) * 16 + l15;
        const int x1 = 2 * (idx >> 6) + cc, y1 = (idx >> 3) & 7, zo = idx & 7;
        const int z1 = o * 8 + zo;
        const int base2 = (x1 * 180 + y1 * 18 + z1) * 2;
        f16x8 bf;
        #pragma unroll
        for (int j = 0; j < 8; ++j)
          bf[j] = *reinterpret_cast<const _Float16*>(tilec + base2 + t_off[j]);
        f32x4 aA = (f32x4){0.f, 0.f, 0.f, 0.f};
        f32x4 aB = (f32x4){0.f, 0.f, 0.f, 0.f};
        aA = __builtin_amdgcn_mfma_f32_16x16x32_f16(__builtin_bit_cast(f16x8, w1a), bf, aA, 0, 0, 0);
        aB = __builtin_amdgcn_mfma_f32_16x16x32_f16(__builtin_bit_cast(f16x8, w1b), bf, aB, 0, 0, 0);

        // epilogue: f32 relu -> cvt_pkrtz -> AND with 0/1 mask
        const unsigned umask = (m1v[(x1 << 7) + (y1 << 4) + z1] != 0.f) ? 0xffffffffu : 0u;
        const int p_l = ((y1 & 1) << 1) | (zo & 1);
        const int v2  = ((x1 >> 1) << 4) | ((y1 >> 1) << 2) | (zo >> 1);
        const int fbase = (((v2 >> 4) * 4 + p_l) * 64 + (v2 & 15)) * 8 + (l4 & 1) * 4;
        const int qsel = l4 >> 1;
        uint2 wA, wB;
        {
          const auto c0 = __builtin_amdgcn_cvt_pkrtz(fmaxf(aA[0], 0.f), fmaxf(aA[1], 0.f));
          const auto c1 = __builtin_amdgcn_cvt_pkrtz(fmaxf(aA[2], 0.f), fmaxf(aA[3], 0.f));
          wA.x = __builtin_bit_cast(unsigned, c0) & umask;
          wA.y = __builtin_bit_cast(unsigned, c1) & umask;
        }
        {
          const auto c0 = __builtin_amdgcn_cvt_pkrtz(fmaxf(aB[0], 0.f), fmaxf(aB[1], 0.f));
          const auto c1 = __builtin_amdgcn_cvt_pkrtz(fmaxf(aB[2], 0.f), fmaxf(aB[3], 0.f));
          wB.x = __builtin_bit_cast(unsigned, c0) & umask;
          wB.y = __builtin_bit_cast(unsigned, c1) & umask;
        }
        *reinterpret_cast<uint2*>(&h1f[fbase + qsel * 128])       = wA;   // ch 0-15
        *reinterpret_cast<uint2*>(&h1f[fbase + (2 + qsel) * 128]) = wB;   // ch 16-31
      }
      __syncthreads();                    // h1f chunk ready

      if (o == 0 && cc == 0 && tid < 16) { // m3 = max over 8 l2 children; [2][2][4]
        const int base = ((tid >> 3) << 6) + (((tid >> 2) & 1) << 4) + ((tid & 3) << 1);
        float m = m2s[base];
        m = fmaxf(m, m2s[base + 1]);  m = fmaxf(m, m2s[base + 8]);
        m = fmaxf(m, m2s[base + 9]);  m = fmaxf(m, m2s[base + 32]);
        m = fmaxf(m, m2s[base + 33]); m = fmaxf(m, m2s[base + 40]);
        m = fmaxf(m, m2s[base + 41]);
        m3s[tid] = m;
      }

      // conv2 partial: K-steps cc*4 .. cc*4+3
      #pragma unroll
      for (int ks = 0; ks < 4; ++ks) {
        const f16x8 af = __builtin_bit_cast(f16x8, w2r[cc * 4 + ks]);
        #pragma unroll
        for (int nt = 0; nt < 4; ++nt) {
          const f16x8 bb = *reinterpret_cast<const f16x8*>(&h1f[((nt * 4 + ks) * 64 + lane) * 8]);
          acc[nt] = __builtin_amdgcn_mfma_f32_16x16x32_f16(af, bb, acc[nt], 0, 0, 0);
        }
      }

      if (o == 1 && cc == 1) {            // prefetch W3 chunk 0 under barrier+epilogue
        #pragma unroll
        for (int j = 0; j < 4; ++j) {
          wa[j]  = W3fA[(wid * 16 + j) * 64 + lane];
          wb2[j] = W3fB[(wid * 16 + j) * 64 + lane];
        }
      }
      __syncthreads();                    // conv2 reads done (h1f reusable)
    }

    // conv2 epilogue: f32 relu -> cvt_pkrtz -> AND m2 mask -> h2s[o]
    _Float16* const h2o = (_Float16*)(smem + o * 11264);
    const int o0 = wid * 16 + l4 * 4;
    #pragma unroll
    for (int nt = 0; nt < 4; ++nt) {
      const int v2l = nt * 16 + l15;
      const float m2v = m2s[((v2l >> 4) << 5) + (((v2l >> 2) & 3) << 3) + o * 4 + (v2l & 3)];
      const unsigned um = (m2v != 0.f) ? 0xffffffffu : 0u;
      const auto p0 = __builtin_amdgcn_cvt_pkrtz(fmaxf(acc[nt][0], 0.f), fmaxf(acc[nt][1], 0.f));
      const auto p1 = __builtin_amdgcn_cvt_pkrtz(fmaxf(acc[nt][2], 0.f), fmaxf(acc[nt][3], 0.f));
      uint2 u;
      u.x = __builtin_bit_cast(unsigned, p0) & um;
      u.y = __builtin_bit_cast(unsigned, p1) & um;
      *reinterpret_cast<uint2*>(&h2o[v2l * 88 + o0]) = u;
    }
  }
  __syncthreads();                        // h2s0 + h2s1 ready

  // ---- conv3 MFMA: N=16 l3-voxels (both octants), K=512, pipelined W3 stream
  f32x4 c3a = (f32x4){0.f,0.f,0.f,0.f};
  f32x4 c3b = (f32x4){0.f,0.f,0.f,0.f};
  const int v3 = l15;                     // [x3 2][y3 2][z3 4]
  const int x3 = v3 >> 3, y3 = (v3 >> 2) & 1, z3 = v3 & 3;
  const int obyte = (z3 >> 1) * 11264;

  #pragma unroll
  for (int kc = 0; kc < 4; ++kc) {
    uint4 na[4], nb[4];
    if (kc < 3) {
      #pragma unroll
      for (int j = 0; j < 4; ++j) {
        na[j] = W3fA[(wid * 16 + (kc + 1) * 4 + j) * 64 + lane];
        nb[j] = W3fB[(wid * 16 + (kc + 1) * 4 + j) * 64 + lane];
      }
    }
    #pragma unroll
    for (int j = 0; j < 4; ++j) {
      const int ks = kc * 4 + j;
      const int p = ks >> 1;
      const int x2 = 2 * x3 + (p >> 2), y2 = 2 * y3 + ((p >> 1) & 1);
      const int z2l = 2 * (z3 & 1) + (p & 1);
      const int v2l = (x2 << 4) | (y2 << 2) | z2l;
      const int c0 = (ks & 1) * 32 + l4 * 8;
      const f16x8 bf = *reinterpret_cast<const f16x8*>(smem + obyte + (v2l * 88 + c0) * 2);
      c3a = __builtin_amdgcn_mfma_f32_16x16x32_f16(__builtin_bit_cast(f16x8, wa[j]),  bf, c3a, 0, 0, 0);
      c3b = __builtin_amdgcn_mfma_f32_16x16x32_f16(__builtin_bit_cast(f16x8, wb2[j]), bf, c3b, 0, 0, 0);
    }
    if (kc < 3) {
      #pragma unroll
      for (int j = 0; j < 4; ++j) { wa[j] = na[j]; wb2[j] = nb[j]; }
    }
  }

  // relu * m3, reduce over the 16 voxel-lanes, bucket atomics
  const float m3v = m3s[v3];
  float part[2][4];
  #pragma unroll
  for (int j = 0; j < 4; ++j) {
    part[0][j] = fmaxf(c3a[j], 0.f) * m3v;
    part[1][j] = fmaxf(c3b[j], 0.f) * m3v;
  }
  #pragma unroll
  for (int d = 1; d < 16; d <<= 1) {
    #pragma unroll
    for (int mt = 0; mt < 2; ++mt)
      #pragma unroll
      for (int j = 0; j < 4; ++j)
        part[mt][j] += __shfl_xor(part[mt][j], d, 64);
  }
  if (l15 == 0) {
    const int sb = (b * 64 + (bid & 63)) * 128 + wid * 32;
    #pragma unroll
    for (int mt = 0; mt < 2; ++mt)
      #pragma unroll
      for (int j = 0; j < 4; ++j)
        atomicAdd(&spart[sb + mt * 16 + l4 * 4 + j], part[mt][j]);
  }
  if (tid == 0) {
    float t = 0.f;
    #pragma unroll
    for (int i = 0; i < 16; ++i) t += m3s[i];
    atomicAdd(&cntB[b * 64 + (bid & 63)], t);
  }
}

// ------------------------------------------------- bucket reduce + final FC
__global__ __launch_bounds__(256) void reduce_fc_k(
    const float* __restrict__ spart, const float* __restrict__ cntB,
    const float* __restrict__ fc_w, const float* __restrict__ fc_b,
    float* __restrict__ out)
{
  __shared__ float s_l[128];
  __shared__ float c_l;
  const int b = blockIdx.x, tid = threadIdx.x;
  if (tid < 128) {
    float a = 0.f;
    #pragma unroll 8
    for (int g = 0; g < 64; ++g) a += spart[(b * 64 + g) * 128 + tid];
    s_l[tid] = a;
  } else if (tid < 192) {
    float a = cntB[b * 64 + (tid - 128)];
    #pragma unroll
    for (int d = 1; d < 64; d <<= 1) a += __shfl_xor(a, d, 64);
    if (tid == 128) c_l = a;
  }
  __syncthreads();
  const float inv = 1.f / fmaxf(c_l, 1.f);
  float o = fc_b[tid];
  #pragma unroll 8
  for (int c = 0; c < 128; ++c) o = fmaf(s_l[c] * inv, fc_w[c * 256 + tid], o);
  out[b * 256 + tid] = o;
}

// ---------------------------------------------------------------- launch
extern "C" void kernel_launch(void* const* d_in, const int* in_sizes, int n_in,
                              void* d_out, int out_size, void* d_ws, size_t ws_size,
                              hipStream_t stream)
{
  const int*   coords = (const int*)  d_in[0];
  const float* feats  = (const float*)d_in[1];
  const float* W1     = (const float*)d_in[2];
  const float* W2     = (const float*)d_in[3];
  const float* W3     = (const float*)d_in[4];
  const float* fc_w   = (const float*)d_in[5];
  const float* fc_b   = (const float*)d_in[6];
  float* out = (float*)d_out;
  const int N = in_sizes[0] / 4;

  unsigned* gpk   = (unsigned*)d_ws;                 // 8.39 MB (f16 val, f16 cnt)
  float*    spart = (float*)(gpk + GRID_ELEMS);      // 256 KB (8 x 64 x 128)
  float*    cntB  = spart + 8 * 64 * 128;            // 2 KB
  uint4*    W1f   = (uint4*)(cntB + 512);            // 2 KB (128 uint4)
  uint4*    W2f   = W1f + 128;                       // 32 KB
  uint4*    W3fA  = W2f + 2048;                      // 64 KB
  uint4*    W3fB  = W3fA + 4096;                     // 64 KB
  // total ws use: ~8.8 MB

  zero_k<<<(ZERO_U4 + 255) / 256, 256, 0, stream>>>((uint4*)gpk);
  scatter_setup_k<<<44 + (N + 255) / 256, 256, 0, stream>>>(
      coords, feats, W1, W2, W3, (__half2*)gpk, W1f, W2f, W3fA, W3fB, N);
  mega_k<<<2048, 256, 0, stream>>>(gpk, W1f, W2f, W3fA, W3fB, spart, cntB);
  reduce_fc_k<<<8, 256, 0, stream>>>(spart, cntB, fc_w, fc_b, out);
}

// Round 13
// 65.430 us; speedup vs baseline: 4.4523x; 1.0556x over previous
//
#include <hip/hip_runtime.h>
#include <hip/hip_bf16.h>
#include <hip/hip_fp16.h>

typedef __attribute__((ext_vector_type(2))) _Float16 f16x2;
typedef __attribute__((ext_vector_type(8))) _Float16 f16x8;
typedef __attribute__((ext_vector_type(4))) float    f32x4;

#define GRID_ELEMS (8*64*64*64)   // 2,097,152 voxels at level 0
#define ZERO_U4    540800         // (GRID_ELEMS*4 + 65536*4 + 512*4) / 16

// ------------------------------------------------------------- fast zeroer
__global__ __launch_bounds__(256) void zero_k(uint4* __restrict__ p)
{
  const unsigned i = blockIdx.x * 256 + threadIdx.x;
  if (i < ZERO_U4) p[i] = (uint4){0u, 0u, 0u, 0u};
}

// --------------------------------------------- scatter + weight-repack combo
// blocks [0,44): pre-fragment W1/W2/W3 into per-lane MFMA A-frag order.
// blocks [44,..): scatter points — ONE packed-f16 atomic adds (feat, 1.0)
// into gpk[voxel] = {lo: f16 value-sum, hi: f16 point-count}.
__global__ __launch_bounds__(256) void scatter_setup_k(
    const int* __restrict__ coords, const float* __restrict__ feats,
    const float* __restrict__ W1, const float* __restrict__ W2, const float* __restrict__ W3,
    __half2* __restrict__ gpk,
    uint4* __restrict__ W1f, uint4* __restrict__ W2f,
    uint4* __restrict__ W3fA, uint4* __restrict__ W3fB, int N)
{
  const int bi = blockIdx.x;
  if (bi < 44) {
    const int i = bi * 256 + threadIdx.x;
    if (i < 2048) {                       // W2f[(wid*8+ks)*64+lane]
      const int wid = i >> 9, ks = (i >> 6) & 7, lane = i & 63;
      const int l15 = lane & 15, l4 = lane >> 4, o = wid * 16 + l15;
      f16x8 v;
      #pragma unroll
      for (int j = 0; j < 8; ++j)          // k = ks*32 + l4*8 + j -> p=ks, c=l4*8+j
        v[j] = (_Float16)W2[ks * 2048 + (l4 * 8 + j) * 64 + o];
      W2f[i] = __builtin_bit_cast(uint4, v);
    } else if (i < 10240) {               // W3fA/B[(wid*16+ks)*64+lane]
      const int e = i - 2048, ab = e >> 12, r = e & 4095;
      const int wid = r >> 10, ks = (r >> 6) & 15, lane = r & 63;
      const int l15 = lane & 15, l4 = lane >> 4, o = wid * 32 + l15 + ab * 16;
      f16x8 v;
      #pragma unroll
      for (int j = 0; j < 8; ++j)          // k = ks*32+l4*8+j -> p=ks>>1, c=(ks&1)*32+l4*8+j
        v[j] = (_Float16)W3[(ks >> 1) * 8192 + ((ks & 1) * 32 + l4 * 8 + j) * 128 + o];
      (ab ? W3fB : W3fA)[r] = __builtin_bit_cast(uint4, v);
    } else if (i < 10368) {               // W1f[mt*64+lane]: A[m=ch][k=tap], k pad 27->32
      const int t = i - 10240;
      const int mt = t >> 6, l = t & 63;
      f16x8 v;
      #pragma unroll
      for (int j = 0; j < 8; ++j) {
        const int k = (l >> 4) * 8 + j;
        v[j] = (k < 27) ? (_Float16)W1[k * 32 + mt * 16 + (l & 15)] : (_Float16)0;
      }
      W1f[t] = __builtin_bit_cast(uint4, v);
    }
    return;
  }
  const int i = (bi - 44) * 256 + threadIdx.x;
  if (i >= N) return;
  const int4 c = reinterpret_cast<const int4*>(coords)[i];
  const int idx = ((c.x * 64 + c.y) * 64 + c.z) * 64 + c.w;
  const __half2 v = __halves2half2(__float2half_rn(feats[i]), __float2half_rn(1.0f));
  unsafeAtomicAdd(&gpk[idx], v);         // global_atomic_pk_add_f16
}

// --------------------------------------------------------------- megakernel
// Block = octant pair: 4x4x8 l2-voxels (8x8x16 l1, 2x2x4 l3). 2048 blocks.
// NEW: conv1 is sparsity-compacted — only ~9% of l1 voxels are occupied, and
// h1 = relu(conv1)*mask is zero elsewhere. Phase 0 builds per-chunk lists of
// occupied voxel ids (LDS append); conv1 zero-fills h1f then computes only
// listed voxels (~2 MFMA groups instead of 16). conv2/conv3 unchanged.
__global__ __launch_bounds__(256, 4) void mega_k(
    const unsigned* __restrict__ gpk,
    const uint4* __restrict__ W1f, const uint4* __restrict__ W2f,
    const uint4* __restrict__ W3fA, const uint4* __restrict__ W3fB,
    float* __restrict__ spart, float* __restrict__ cntB)
{
  // LDS carve (36,960 B): [h2s0 11264][h1f 16384 (h2s1 overlays)]
  // [tile 3600][m1v 4096][m2s 512][m3s 64][lists 1024][lcnt 16]
  __shared__ __align__(16) char smem[36960];
  _Float16* const h1f  = (_Float16*)(smem + 11264);
  _Float16* const tile = (_Float16*)(smem + 27648);        // [10][10][18]
  float*    const m1v  = (float*)(smem + 31248);           // [8][8][16]
  float*    const m2s  = (float*)(smem + 35344);           // [4][4][8]
  float*    const m3s  = (float*)(smem + 35856);           // [2][2][4]
  unsigned char* const lists = (unsigned char*)(smem + 35920); // [4][256]
  int*      const lcnt = (int*)(smem + 36944);             // [4]

  const int tid = threadIdx.x;
  const int bid = blockIdx.x;
  const int b   = bid >> 8;
  const int X2  = (bid >> 5) & 7, Y2 = (bid >> 2) & 7, Zp = bid & 3;
  const int gb  = b << 18;
  const int lane = tid & 63, wid = tid >> 6;
  const int l15 = lane & 15, l4 = lane >> 4;

  if (tid < 4) lcnt[tid] = 0;
  __syncthreads();

  // ---- phase 0: stage grid tile (f16 val half) + l1 mask + occupied lists
  {
    const int gx0 = X2 * 8 - 1, gy0 = Y2 * 8 - 1, gz0 = Zp * 16 - 1;
    for (int e = tid; e < 1800; e += 256) {
      const int x = e / 180, r = e - x * 180, y = r / 18, z = r - y * 18;
      const int gx = gx0 + x, gy = gy0 + y, gz = gz0 + z;
      const bool ok = ((unsigned)gx < 64u) & ((unsigned)gy < 64u) & ((unsigned)gz < 64u);
      const unsigned g = ok ? gpk[gb + (gx << 12) + (gy << 6) + gz] : 0u;
      tile[e] = __builtin_bit_cast(_Float16, (unsigned short)(g & 0xffffu));
      const int ix = x - 1, iy = y - 1, iz = z - 1;
      if (((unsigned)ix < 8u) & ((unsigned)iy < 8u) & ((unsigned)iz < 16u)) {
        const bool occ = (g >> 16) != 0u;
        m1v[(ix << 7) + (iy << 4) + iz] = occ ? 1.f : 0.f;
        if (occ) {                         // append to chunk (o = iz>>3, cc = ix&1)
          const int li = ((iz >> 3) << 1) | (ix & 1);
          const int slot = atomicAdd(&lcnt[li], 1);
          lists[li * 256 + slot] =
              (unsigned char)(((ix >> 1) << 6) | (iy << 3) | (iz & 7));
        }
      }
    }
  }

  // W-frag preloads (L2; latency hidden under phase 0)
  const uint4 w1a = W1f[lane];
  const uint4 w1b = W1f[64 + lane];
  uint4 w2r[8];
  #pragma unroll
  for (int ks = 0; ks < 8; ++ks) w2r[ks] = W2f[(wid * 8 + ks) * 64 + lane];

  // tap byte-offsets, computed arithmetically (pad k>=27 -> offset 0)
  int t_off[8];
  #pragma unroll
  for (int j = 0; j < 8; ++j) {
    const int k = l4 * 8 + j;
    int off = 0;
    if (k < 27) {
      const int tx = k / 9, rr = k - 9 * tx, ty = rr / 3, tz = rr - 3 * ty;
      off = (tx * 180 + ty * 18 + tz) * 2;
    }
    t_off[j] = off;
  }

  __syncthreads();

  if (tid < 128) {   // m2 = max over 8 l1 children; [x2][y2][z2] 4x4x8
    const int base = ((tid >> 5) << 8) + (((tid >> 3) & 3) << 5) + ((tid & 7) << 1);
    float m = m1v[base];
    m = fmaxf(m, m1v[base + 1]);   m = fmaxf(m, m1v[base + 16]);
    m = fmaxf(m, m1v[base + 17]);  m = fmaxf(m, m1v[base + 128]);
    m = fmaxf(m, m1v[base + 129]); m = fmaxf(m, m1v[base + 144]);
    m = fmaxf(m, m1v[base + 145]);
    m2s[tid] = m;
  }

  const char* tilec = (const char*)tile;
  uint4 wa[4], wb2[4];                    // W3 pipeline regs (filled at o==1)

  #pragma unroll
  for (int o = 0; o < 2; ++o) {
    f32x4 acc[4];
    #pragma unroll
    for (int nt = 0; nt < 4; ++nt) acc[nt] = (f32x4){0.f, 0.f, 0.f, 0.f};

    #pragma unroll
    for (int cc = 0; cc < 2; ++cc) {
      // ---- zero h1f (prev chunk's reads done at trailing barrier)
      {
        uint4* zp = reinterpret_cast<uint4*>((char*)h1f + tid * 64);
        const uint4 z4 = (uint4){0u, 0u, 0u, 0u};
        zp[0] = z4; zp[1] = z4; zp[2] = z4; zp[3] = z4;
      }
      __syncthreads();

      // ---- conv1 MFMA over the occupied-voxel list only (~2 groups/chunk)
      const int lc = lcnt[o * 2 + cc];
      for (int g = wid; g * 16 < lc; g += 4) {
        const int slot = g * 16 + l15;
        const bool valid = slot < lc;
        const int idx = valid ? (int)lists[(o * 2 + cc) * 256 + slot] : 0;
        const int x1 = 2 * (idx >> 6) + cc, y1 = (idx >> 3) & 7, zo = idx & 7;
        const int z1 = o * 8 + zo;
        const int base2 = (x1 * 180 + y1 * 18 + z1) * 2;
        f16x8 bf;
        #pragma unroll
        for (int j = 0; j < 8; ++j)
          bf[j] = *reinterpret_cast<const _Float16*>(tilec + base2 + t_off[j]);
        f32x4 aA = (f32x4){0.f, 0.f, 0.f, 0.f};
        f32x4 aB = (f32x4){0.f, 0.f, 0.f, 0.f};
        aA = __builtin_amdgcn_mfma_f32_16x16x32_f16(__builtin_bit_cast(f16x8, w1a), bf, aA, 0, 0, 0);
        aB = __builtin_amdgcn_mfma_f32_16x16x32_f16(__builtin_bit_cast(f16x8, w1b), bf, aB, 0, 0, 0);

        if (valid) {                      // listed => mask == 1, just relu
          const int p_l = ((y1 & 1) << 1) | (zo & 1);
          const int v2  = ((x1 >> 1) << 4) | ((y1 >> 1) << 2) | (zo >> 1);
          const int fbase = (((v2 >> 4) * 4 + p_l) * 64 + (v2 & 15)) * 8 + (l4 & 1) * 4;
          const int qsel = l4 >> 1;
          uint2 wA, wB;
          {
            const auto c0 = __builtin_amdgcn_cvt_pkrtz(fmaxf(aA[0], 0.f), fmaxf(aA[1], 0.f));
            const auto c1 = __builtin_amdgcn_cvt_pkrtz(fmaxf(aA[2], 0.f), fmaxf(aA[3], 0.f));
            wA.x = __builtin_bit_cast(unsigned, c0);
            wA.y = __builtin_bit_cast(unsigned, c1);
          }
          {
            const auto c0 = __builtin_amdgcn_cvt_pkrtz(fmaxf(aB[0], 0.f), fmaxf(aB[1], 0.f));
            const auto c1 = __builtin_amdgcn_cvt_pkrtz(fmaxf(aB[2], 0.f), fmaxf(aB[3], 0.f));
            wB.x = __builtin_bit_cast(unsigned, c0);
            wB.y = __builtin_bit_cast(unsigned, c1);
          }
          *reinterpret_cast<uint2*>(&h1f[fbase + qsel * 128])       = wA;   // ch 0-15
          *reinterpret_cast<uint2*>(&h1f[fbase + (2 + qsel) * 128]) = wB;   // ch 16-31
        }
      }
      __syncthreads();                    // h1f chunk ready

      if (o == 0 && cc == 0 && tid < 16) { // m3 = max over 8 l2 children; [2][2][4]
        const int base = ((tid >> 3) << 6) + (((tid >> 2) & 1) << 4) + ((tid & 3) << 1);
        float m = m2s[base];
        m = fmaxf(m, m2s[base + 1]);  m = fmaxf(m, m2s[base + 8]);
        m = fmaxf(m, m2s[base + 9]);  m = fmaxf(m, m2s[base + 32]);
        m = fmaxf(m, m2s[base + 33]); m = fmaxf(m, m2s[base + 40]);
        m = fmaxf(m, m2s[base + 41]);
        m3s[tid] = m;
      }

      // conv2 partial: K-steps cc*4 .. cc*4+3
      #pragma unroll
      for (int ks = 0; ks < 4; ++ks) {
        const f16x8 af = __builtin_bit_cast(f16x8, w2r[cc * 4 + ks]);
        #pragma unroll
        for (int nt = 0; nt < 4; ++nt) {
          const f16x8 bb = *reinterpret_cast<const f16x8*>(&h1f[((nt * 4 + ks) * 64 + lane) * 8]);
          acc[nt] = __builtin_amdgcn_mfma_f32_16x16x32_f16(af, bb, acc[nt], 0, 0, 0);
        }
      }

      if (o == 1 && cc == 1) {            // prefetch W3 chunk 0 under barrier+epilogue
        #pragma unroll
        for (int j = 0; j < 4; ++j) {
          wa[j]  = W3fA[(wid * 16 + j) * 64 + lane];
          wb2[j] = W3fB[(wid * 16 + j) * 64 + lane];
        }
      }
      __syncthreads();                    // conv2 reads done (h1f reusable)
    }

    // conv2 epilogue: f32 relu -> cvt_pkrtz -> AND m2 mask -> h2s[o]
    _Float16* const h2o = (_Float16*)(smem + o * 11264);
    const int o0 = wid * 16 + l4 * 4;
    #pragma unroll
    for (int nt = 0; nt < 4; ++nt) {
      const int v2l = nt * 16 + l15;
      const float m2v = m2s[((v2l >> 4) << 5) + (((v2l >> 2) & 3) << 3) + o * 4 + (v2l & 3)];
      const unsigned um = (m2v != 0.f) ? 0xffffffffu : 0u;
      const auto p0 = __builtin_amdgcn_cvt_pkrtz(fmaxf(acc[nt][0], 0.f), fmaxf(acc[nt][1], 0.f));
      const auto p1 = __builtin_amdgcn_cvt_pkrtz(fmaxf(acc[nt][2], 0.f), fmaxf(acc[nt][3], 0.f));
      uint2 u;
      u.x = __builtin_bit_cast(unsigned, p0) & um;
      u.y = __builtin_bit_cast(unsigned, p1) & um;
      *reinterpret_cast<uint2*>(&h2o[v2l * 88 + o0]) = u;
    }
  }
  __syncthreads();                        // h2s0 + h2s1 ready

  // ---- conv3 MFMA: N=16 l3-voxels (both octants), K=512, pipelined W3 stream
  f32x4 c3a = (f32x4){0.f,0.f,0.f,0.f};
  f32x4 c3b = (f32x4){0.f,0.f,0.f,0.f};
  const int v3 = l15;                     // [x3 2][y3 2][z3 4]
  const int x3 = v3 >> 3, y3 = (v3 >> 2) & 1, z3 = v3 & 3;
  const int obyte = (z3 >> 1) * 11264;

  #pragma unroll
  for (int kc = 0; kc < 4; ++kc) {
    uint4 na[4], nb[4];
    if (kc < 3) {
      #pragma unroll
      for (int j = 0; j < 4; ++j) {
        na[j] = W3fA[(wid * 16 + (kc + 1) * 4 + j) * 64 + lane];
        nb[j] = W3fB[(wid * 16 + (kc + 1) * 4 + j) * 64 + lane];
      }
    }
    #pragma unroll
    for (int j = 0; j < 4; ++j) {
      const int ks = kc * 4 + j;
      const int p = ks >> 1;
      const int x2 = 2 * x3 + (p >> 2), y2 = 2 * y3 + ((p >> 1) & 1);
      const int z2l = 2 * (z3 & 1) + (p & 1);
      const int v2l = (x2 << 4) | (y2 << 2) | z2l;
      const int c0 = (ks & 1) * 32 + l4 * 8;
      const f16x8 bf = *reinterpret_cast<const f16x8*>(smem + obyte + (v2l * 88 + c0) * 2);
      c3a = __builtin_amdgcn_mfma_f32_16x16x32_f16(__builtin_bit_cast(f16x8, wa[j]),  bf, c3a, 0, 0, 0);
      c3b = __builtin_amdgcn_mfma_f32_16x16x32_f16(__builtin_bit_cast(f16x8, wb2[j]), bf, c3b, 0, 0, 0);
    }
    if (kc < 3) {
      #pragma unroll
      for (int j = 0; j < 4; ++j) { wa[j] = na[j]; wb2[j] = nb[j]; }
    }
  }

  // relu * m3, reduce over the 16 voxel-lanes, bucket atomics
  const float m3v = m3s[v3];
  float part[2][4];
  #pragma unroll
  for (int j = 0; j < 4; ++j) {
    part[0][j] = fmaxf(c3a[j], 0.f) * m3v;
    part[1][j] = fmaxf(c3b[j], 0.f) * m3v;
  }
  #pragma unroll
  for (int d = 1; d < 16; d <<= 1) {
    #pragma unroll
    for (int mt = 0; mt < 2; ++mt)
      #pragma unroll
      for (int j = 0; j < 4; ++j)
        part[mt][j] += __shfl_xor(part[mt][j], d, 64);
  }
  if (l15 == 0) {
    const int sb = (b * 64 + (bid & 63)) * 128 + wid * 32;
    #pragma unroll
    for (int mt = 0; mt < 2; ++mt)
      #pragma unroll
      for (int j = 0; j < 4; ++j)
        atomicAdd(&spart[sb + mt * 16 + l4 * 4 + j], part[mt][j]);
  }
  if (tid == 0) {
    float t = 0.f;
    #pragma unroll
    for (int i = 0; i < 16; ++i) t += m3s[i];
    atomicAdd(&cntB[b * 64 + (bid & 63)], t);
  }
}

// ------------------------------------------------- bucket reduce + final FC
__global__ __launch_bounds__(256) void reduce_fc_k(
    const float* __restrict__ spart, const float* __restrict__ cntB,
    const float* __restrict__ fc_w, const float* __restrict__ fc_b,
    float* __restrict__ out)
{
  __shared__ float s_l[128];
  __shared__ float c_l;
  const int b = blockIdx.x, tid = threadIdx.x;
  if (tid < 128) {
    float a = 0.f;
    #pragma unroll 8
    for (int g = 0; g < 64; ++g) a += spart[(b * 64 + g) * 128 + tid];
    s_l[tid] = a;
  } else if (tid < 192) {
    float a = cntB[b * 64 + (tid - 128)];
    #pragma unroll
    for (int d = 1; d < 64; d <<= 1) a += __shfl_xor(a, d, 64);
    if (tid == 128) c_l = a;
  }
  __syncthreads();
  const float inv = 1.f / fmaxf(c_l, 1.f);
  float o = fc_b[tid];
  #pragma unroll 8
  for (int c = 0; c < 128; ++c) o = fmaf(s_l[c] * inv, fc_w[c * 256 + tid], o);
  out[b * 256 + tid] = o;
}

// ---------------------------------------------------------------- launch
extern "C" void kernel_launch(void* const* d_in, const int* in_sizes, int n_in,
                              void* d_out, int out_size, void* d_ws, size_t ws_size,
                              hipStream_t stream)
{
  const int*   coords = (const int*)  d_in[0];
  const float* feats  = (const float*)d_in[1];
  const float* W1     = (const float*)d_in[2];
  const float* W2     = (const float*)d_in[3];
  const float* W3     = (const float*)d_in[4];
  const float* fc_w   = (const float*)d_in[5];
  const float* fc_b   = (const float*)d_in[6];
  float* out = (float*)d_out;
  const int N = in_sizes[0] / 4;

  unsigned* gpk   = (unsigned*)d_ws;                 // 8.39 MB (f16 val, f16 cnt)
  float*    spart = (float*)(gpk + GRID_ELEMS);      // 256 KB (8 x 64 x 128)
  float*    cntB  = spart + 8 * 64 * 128;            // 2 KB
  uint4*    W1f   = (uint4*)(cntB + 512);            // 2 KB (128 uint4)
  uint4*    W2f   = W1f + 128;                       // 32 KB
  uint4*    W3fA  = W2f + 2048;                      // 64 KB
  uint4*    W3fB  = W3fA + 4096;                     // 64 KB
  // total ws use: ~8.8 MB

  zero_k<<<(ZERO_U4 + 255) / 256, 256, 0, stream>>>((uint4*)gpk);
  scatter_setup_k<<<44 + (N + 255) / 256, 256, 0, stream>>>(
      coords, feats, W1, W2, W3, (__half2*)gpk, W1f, W2f, W3fA, W3fB, N);
  mega_k<<<2048, 256, 0, stream>>>(gpk, W1f, W2f, W3fA, W3fB, spart, cntB);
  reduce_fc_k<<<8, 256, 0, stream>>>(spart, cntB, fc_w, fc_b, out);
}